// Round 7
// baseline (228.938 us; speedup 1.0000x reference)
//
#include <hip/hip_runtime.h>

// Correlation layer via banded bf16 MFMA, two-pass (gfx950).
// out[b, dy*9+dx, y, x] = sum_c f1[b,c,y,x] * f2[b,c,y+dy-4,x+dx-4]
//
// R7: R6's pass2 was latency-bound (VGPR=36 -> ~3 loads in flight, MfmaUtil
// 4%, VALU 11%). Changes:
//  - pass 1 converts BOTH inputs once to fragment-ready bf16 layouts in d_ws:
//      w2: [b][c/8][y'=72][x'=144][c%8]  (zero halos baked in, 42.5 MB)
//      w1: [b][c/8][y =64][x =128][c%8]  (33.5 MB)
//    one thread = one uint4 out (coalesced 16B stores, lane-contiguous reads).
//  - pass 2: per K-chunk of 32ch: 1 A dwordx4 + 10 B dwordx4 + 10 MFMAs,
//    no VALU packing, explicit 1-chunk-ahead register double-buffer prefetch
//    (fully unrolled, no LDS, no barriers -> 11 loads in flight per wave).
// B-tiles at x' = 16j tile exactly; band extraction in epilogue (validated
// R5/R6, absmax 0.5).

namespace {
constexpr int B_ = 8, C_ = 256, H_ = 64, W_ = 128;
constexpr int SIDE = 9, ND = 81, PAD = 4;
constexpr int HW = H_ * W_;
constexpr int CB = 32;              // channel-blocks of 8
constexpr int HP = 72, WP = 144;    // padded f2 dims (y' = y+dy, x' = x+4)
constexpr size_t NF2 = (size_t)B_ * CB * HP * WP;   // 2,654,208 uint4
constexpr size_t NF1 = (size_t)B_ * CB * H_ * W_;   // 2,097,152 uint4
constexpr size_t WS_BYTES = (NF2 + NF1) * 16;       // ~76 MB
}

typedef __attribute__((ext_vector_type(8))) short short8;
typedef __attribute__((ext_vector_type(4))) float float4v;

__device__ __forceinline__ unsigned bf16rne(float f) {
  unsigned u = __float_as_uint(f);
  return (u + 0x7fffu + ((u >> 16) & 1u)) >> 16;
}
__device__ __forceinline__ unsigned packbf2(float lo, float hi) {
  return bf16rne(lo) | (bf16rne(hi) << 16);
}

// ---------------- pass 1: both inputs -> fragment-ready bf16 ----------------
__global__ __launch_bounds__(256)
void cvt_both(const float* __restrict__ f1, const float* __restrict__ f2,
              uint4* __restrict__ w1, uint4* __restrict__ w2) {
  const size_t tid = (size_t)blockIdx.x * 256 + threadIdx.x;
  if (tid < NF2) {
    // w2 index: ((b*CB+cb)*HP + yp)*WP + xp
    const int xp = (int)(tid % WP);
    size_t r = tid / WP;
    const int yp = (int)(r % HP);
    r /= HP;
    const int cb = (int)(r % CB);
    const int b = (int)(r / CB);
    const int yg = yp - PAD, xg = xp - PAD;
    uint4 o = {0u, 0u, 0u, 0u};
    if (yg >= 0 && yg < H_ && xg >= 0 && xg < W_) {
      const float* s = f2 + ((size_t)(b * C_ + cb * 8) * H_ + yg) * W_ + xg;
      o.x = packbf2(s[0 * HW], s[1 * HW]);
      o.y = packbf2(s[2 * HW], s[3 * HW]);
      o.z = packbf2(s[4 * HW], s[5 * HW]);
      o.w = packbf2(s[6 * HW], s[7 * HW]);
    }
    w2[tid] = o;
  } else {
    const size_t t2 = tid - NF2;
    const int x = (int)(t2 % W_);
    size_t r = t2 / W_;
    const int y = (int)(r % H_);
    r /= H_;
    const int cb = (int)(r % CB);
    const int b = (int)(r / CB);
    const float* s = f1 + ((size_t)(b * C_ + cb * 8) * H_ + y) * W_ + x;
    uint4 o;
    o.x = packbf2(s[0 * HW], s[1 * HW]);
    o.y = packbf2(s[2 * HW], s[3 * HW]);
    o.z = packbf2(s[4 * HW], s[5 * HW]);
    o.w = packbf2(s[6 * HW], s[7 * HW]);
    w1[t2] = o;
  }
}

// ---------------- pass 2: banded MFMA, prefetched register pipeline ----------
__global__ __launch_bounds__(256, 4)
void corr_mfma(const uint4* __restrict__ w1, const uint4* __restrict__ w2,
               float* __restrict__ out) {
  const int t = threadIdx.x;
  const int lane = t & 63;
  const int wv = t >> 6;                      // 0..3
  const int jm = blockIdx.x * 2 + (wv >> 1);  // M-tile 0..7 (x = 16*jm..)
  const int half = wv & 1;                    // dy half: 0 -> dy 0..4, 1 -> 5..8
  const int y = blockIdx.y;
  const int b = blockIdx.z;
  const int v = lane & 15;                    // fragment pixel index
  const int q = lane >> 4;                    // k-quad / C-row-group
  const int dyb = half * 5;
  const int ndy = 5 - half;

  float4v acc0[5], acc1[5];
#pragma unroll
  for (int i = 0; i < 5; ++i) {
    acc0[i] = (float4v){0.f, 0.f, 0.f, 0.f};
    acc1[i] = (float4v){0.f, 0.f, 0.f, 0.f};
  }

  // chunk ch uses channel-blocks cb = ch*4 + q
  const uint4* a_base =
      w1 + ((size_t)(b * CB + q) * H_ + y) * W_ + 16 * jm + v;
  const uint4* b_base =
      w2 + ((size_t)(b * CB + q) * HP + (y + dyb)) * WP + 16 * jm + v;

  uint4 A[2];
  uint4 Bv[2][10];

  auto load_chunk = [&](int ch, int s) {
    A[s] = a_base[(size_t)ch * 4 * (H_ * W_)];
    const uint4* bc = b_base + (size_t)ch * 4 * (HP * WP);
#pragma unroll
    for (int i = 0; i < 5; ++i) {
      if (i < ndy) {
        Bv[s][2 * i] = bc[(size_t)i * WP];
        Bv[s][2 * i + 1] = bc[(size_t)i * WP + 16];
      }
    }
  };

  load_chunk(0, 0);
#pragma unroll
  for (int ch = 0; ch < 8; ++ch) {
    const int s = ch & 1;
    if (ch < 7) load_chunk(ch + 1, s ^ 1);
    const short8 af = __builtin_bit_cast(short8, A[s]);
#pragma unroll
    for (int i = 0; i < 5; ++i) {
      if (i < ndy) {
        acc0[i] = __builtin_amdgcn_mfma_f32_16x16x32_bf16(
            af, __builtin_bit_cast(short8, Bv[s][2 * i]), acc0[i], 0, 0, 0);
        acc1[i] = __builtin_amdgcn_mfma_f32_16x16x32_bf16(
            af, __builtin_bit_cast(short8, Bv[s][2 * i + 1]), acc1[i], 0, 0, 0);
      }
    }
  }

  // Epilogue: C/D col n = v, row m = q*4+reg. tile0: dx = n-m in [0,8];
  // tile1: dx = n-m+16 in [1,8]. Each output element written exactly once.
#pragma unroll
  for (int i = 0; i < 5; ++i) {
    if (i < ndy) {
      const int dy = dyb + i;
#pragma unroll
      for (int r = 0; r < 4; ++r) {
        const int m = q * 4 + r;
        const int x = 16 * jm + m;
        const int dx0 = v - m;
        if (dx0 >= 0 && dx0 <= 8)
          out[(((size_t)b * ND + dy * SIDE + dx0) * H_ + y) * W_ + x] = acc0[i][r];
        const int dx1 = v - m + 16;
        if (dx1 <= 8)
          out[(((size_t)b * ND + dy * SIDE + dx1) * H_ + y) * W_ + x] = acc1[i][r];
      }
    }
  }
}

// ---------------- fallback (R5 kernel) if ws_size is too small ----------------
namespace fb {
constexpr int PXS = 20, F2PX = 80, F1PX = 64, KC = 32, NCH = C_ / KC;
constexpr int F2U = SIDE * (F2PX / 4) * (KC / 2);
constexpr int F1U = (F1PX / 4) * (KC / 2);
constexpr int NU = F2U + F1U;
}

__global__ __launch_bounds__(512, 4)
void corr_fallback(const float* __restrict__ f1, const float* __restrict__ f2,
                   float* __restrict__ out) {
  using namespace fb;
  __shared__ __align__(16) unsigned f2s[SIDE * F2PX * PXS];
  __shared__ __align__(16) unsigned f1s[F1PX * PXS];

  const int t = threadIdx.x;
  const int bx = blockIdx.x, by = blockIdx.y, b = blockIdx.z;
  const int x0B = bx * 64;
  const int lane = t & 63, wv = t >> 6;
  const int wt = wv >> 1, half = wv & 1;
  const int dyb = half * 5, ndy = 5 - half;
  const int v = lane & 15, q = lane >> 4;

  float4v acc0[5], acc1[5];
#pragma unroll
  for (int i = 0; i < 5; ++i) {
    acc0[i] = (float4v){0.f, 0.f, 0.f, 0.f};
    acc1[i] = (float4v){0.f, 0.f, 0.f, 0.f};
  }
  const float* __restrict__ f1b = f1 + (size_t)b * C_ * HW;
  const float* __restrict__ f2b = f2 + (size_t)b * C_ * HW;

  for (int ch = 0; ch < NCH; ++ch) {
    const int c0 = ch * KC;
    if (ch) __syncthreads();
    for (int u = t; u < NU; u += 512) {
      if (u < F2U) {
        const int cp = u & 15;
        const int rp = u >> 4;
        const int pxq = rp % 20;
        const int r = rp / 20;
        const int yg = by + r - PAD;
        const int xb = x0B - PAD + pxq * 4;
        float4 va = make_float4(0.f, 0.f, 0.f, 0.f), vb = va;
        if (yg >= 0 && yg < H_ && xb >= 0 && xb <= W_ - 4) {
          const float* p = f2b + ((size_t)(c0 + 2 * cp) * H_ + yg) * W_ + xb;
          va = *(const float4*)p;
          vb = *(const float4*)(p + HW);
        }
        unsigned* d = &f2s[(r * F2PX + pxq * 4) * PXS + cp];
        d[0 * PXS] = packbf2(va.x, vb.x);
        d[1 * PXS] = packbf2(va.y, vb.y);
        d[2 * PXS] = packbf2(va.z, vb.z);
        d[3 * PXS] = packbf2(va.w, vb.w);
      } else {
        const int u2 = u - F2U;
        const int cp = u2 & 15;
        const int pxq = u2 >> 4;
        const float* p = f1b + ((size_t)(c0 + 2 * cp) * H_ + by) * W_ + x0B + pxq * 4;
        const float4 va = *(const float4*)p;
        const float4 vb = *(const float4*)(p + HW);
        unsigned* d = &f1s[(pxq * 4) * PXS + cp];
        d[0 * PXS] = packbf2(va.x, vb.x);
        d[1 * PXS] = packbf2(va.y, vb.y);
        d[2 * PXS] = packbf2(va.z, vb.z);
        d[3 * PXS] = packbf2(va.w, vb.w);
      }
    }
    __syncthreads();

    const short8 af =
        __builtin_bit_cast(short8, *(const uint4*)&f1s[(16 * wt + v) * PXS + 4 * q]);
#pragma unroll
    for (int i = 0; i < 5; ++i) {
      if (i < ndy) {
        const int dy = dyb + i;
        const unsigned* fbp = &f2s[(dy * F2PX + 16 * wt + v) * PXS + 4 * q];
        const short8 b0 = __builtin_bit_cast(short8, *(const uint4*)fbp);
        const short8 b1 = __builtin_bit_cast(short8, *(const uint4*)(fbp + 16 * PXS));
        acc0[i] = __builtin_amdgcn_mfma_f32_16x16x32_bf16(af, b0, acc0[i], 0, 0, 0);
        acc1[i] = __builtin_amdgcn_mfma_f32_16x16x32_bf16(af, b1, acc1[i], 0, 0, 0);
      }
    }
  }
#pragma unroll
  for (int i = 0; i < 5; ++i) {
    if (i < ndy) {
      const int dy = dyb + i;
#pragma unroll
      for (int r = 0; r < 4; ++r) {
        const int m = q * 4 + r;
        const int x = x0B + 16 * wt + m;
        const int dx0 = v - m;
        if (dx0 >= 0 && dx0 <= 8)
          out[(((size_t)b * ND + dy * SIDE + dx0) * H_ + by) * W_ + x] = acc0[i][r];
        const int dx1 = v - m + 16;
        if (dx1 <= 8)
          out[(((size_t)b * ND + dy * SIDE + dx1) * H_ + by) * W_ + x] = acc1[i][r];
      }
    }
  }
}

extern "C" void kernel_launch(void* const* d_in, const int* in_sizes, int n_in,
                              void* d_out, int out_size, void* d_ws, size_t ws_size,
                              hipStream_t stream) {
  const float* f1 = (const float*)d_in[0];
  const float* f2 = (const float*)d_in[1];
  float* out = (float*)d_out;

  if (ws_size >= WS_BYTES) {
    uint4* w2 = (uint4*)d_ws;
    uint4* w1 = w2 + NF2;
    const int nthreads = (int)(NF2 + NF1);            // both multiples of 256
    cvt_both<<<dim3(nthreads / 256), 256, 0, stream>>>(f1, f2, w1, w2);
    corr_mfma<<<dim3(4, H_, B_), 256, 0, stream>>>(w1, w2, out);
  } else {
    corr_fallback<<<dim3(2, H_, B_), 512, 0, stream>>>(f1, f2, out);
  }
}